// Round 4
// baseline (312.574 us; speedup 1.0000x reference)
//
#include <hip/hip_runtime.h>
#include <hip/hip_bf16.h>

// Problem constants (from reference)
#define B 16
#define C 128
#define H 192
#define W 192
#define HID 32
#define K 2
#define PLANE (H*W)           // 36864
#define NPLANES (B*C)         // 2048
#define RB 6                  // output rows per thread

typedef float floatx4 __attribute__((ext_vector_type(4)));

// ---------------- Kernel 1: global average pool per (b,c) plane ----------------
__global__ __launch_bounds__(256) void pool_kernel(const float* __restrict__ x,
                                                   float* __restrict__ pooled) {
    const int plane = blockIdx.x;  // b*C + c
    const float4* px4 = (const float4*)(x + (size_t)plane * PLANE);  // 9216 float4
    float s = 0.f;
    for (int i = threadIdx.x; i < PLANE / 4; i += 256) {
        float4 v = px4[i];
        s += v.x + v.y + v.z + v.w;
    }
    // wave64 reduce
    for (int off = 32; off; off >>= 1) s += __shfl_down(s, off, 64);
    __shared__ float wsum[4];
    const int lane = threadIdx.x & 63, wid = threadIdx.x >> 6;
    if (lane == 0) wsum[wid] = s;
    __syncthreads();
    if (threadIdx.x == 0) {
        pooled[plane] = (wsum[0] + wsum[1] + wsum[2] + wsum[3]) * (1.0f / (float)PLANE);
    }
}

// ---------------- Kernel 2: selector MLP + softmax + weight combine ----------------
__global__ __launch_bounds__(512) void selector_kernel(const float* __restrict__ pooled,
                                                       const float* __restrict__ w1,
                                                       const float* __restrict__ b1,
                                                       const float* __restrict__ w2,
                                                       const float* __restrict__ b2,
                                                       const float* __restrict__ wb,
                                                       float* __restrict__ cw) {
    __shared__ float h[B][HID];
    __shared__ float attn[B][K];
    const int tid = threadIdx.x;

    // h[b][j] = relu(sum_c pooled[b,c] * w1[j,c] + b1[j])   (512 = 16*32 threads)
    {
        const int b = tid >> 5, j = tid & 31;
        float s = b1[j];
        const float* pb = pooled + b * C;
        const float* wj = w1 + j * C;
        #pragma unroll 8
        for (int c = 0; c < C; ++c) s += pb[c] * wj[c];
        h[b][j] = fmaxf(s, 0.f);
    }
    __syncthreads();
    // logits[b][k]
    if (tid < B * K) {
        const int b = tid >> 1, k = tid & 1;
        float s = b2[k];
        const float* wk = w2 + k * HID;
        #pragma unroll
        for (int j = 0; j < HID; ++j) s += h[b][j] * wk[j];
        attn[b][k] = s;
    }
    __syncthreads();
    // softmax over K=2
    if (tid < B) {
        const float a0 = attn[tid][0], a1 = attn[tid][1];
        const float m = fmaxf(a0, a1);
        const float e0 = __expf(a0 - m), e1 = __expf(a1 - m);
        const float inv = 1.f / (e0 + e1);
        attn[tid][0] = e0 * inv;
        attn[tid][1] = e1 * inv;
    }
    __syncthreads();
    // cw[b][c][9] = attn[b][0]*wb[0][c][9] + attn[b][1]*wb[1][c][9]
    for (int i = tid; i < B * C * 9; i += 512) {
        const int b = i / (C * 9);
        const int ci = i % (C * 9);
        cw[i] = attn[b][0] * wb[ci] + attn[b][1] * wb[C * 9 + ci];
    }
}

// ---------------- Kernel 3: depthwise 3x3 conv (pad 1) + bias ----------------
// Tiling: thread = 12-wide x 6-tall output tile. 16 strips/row -> 16 lanes
// per image row, wave = 4 rows. Per input row: 3 ALIGNED float4 loads; the
// left/right halo elements come from neighbor lanes via __shfl (width 16) --
// no scalar loads, no unaligned loads, no cross-plane/OOB reads.
// Block = 512 threads = one full plane (32 bands x 16 strips).
// Planes iterate in REVERSE so conv reads the tail of x that pool_kernel
// left resident in the 256 MiB Infinity Cache (x = 302 MB).
__global__ __launch_bounds__(512) void conv_kernel(const float* __restrict__ x,
                                                   const float* __restrict__ cw,
                                                   const float* __restrict__ bias,
                                                   float* __restrict__ out) {
    const int plane = (NPLANES - 1) - blockIdx.x;   // reverse order, block-uniform
    const int tid   = threadIdx.x;
    const int strip = tid & 15;        // 12-float column strip
    const int band  = tid >> 4;        // 0..31, RB rows each
    const int c     = plane & (C - 1);

    const float* w = cw + plane * 9;
    const float w00 = w[0], w01 = w[1], w02 = w[2];
    const float w10 = w[3], w11 = w[4], w12 = w[5];
    const float w20 = w[6], w21 = w[7], w22 = w[8];
    const float bv = bias[c];

    const int x0 = strip * 12;
    const int y0 = band * RB;
    const float* px = x + (size_t)plane * PLANE;

    float acc[RB][12];
    #pragma unroll
    for (int j = 0; j < RB; ++j)
        #pragma unroll
        for (int q = 0; q < 12; ++q) acc[j][q] = bv;

    #pragma unroll
    for (int i = 0; i < RB + 2; ++i) {
        const int r = y0 - 1 + i;
        floatx4 A = {0.f, 0.f, 0.f, 0.f};
        floatx4 Bv = {0.f, 0.f, 0.f, 0.f};
        floatx4 Cv = {0.f, 0.f, 0.f, 0.f};
        if (r >= 0 && r < H) {
            const floatx4* rp = (const floatx4*)(px + r * W + x0);
            A = rp[0]; Bv = rp[1]; Cv = rp[2];
        }
        // halos from neighbor lanes (same band => same r within 16-lane group)
        float vL = __shfl_up(Cv.w, 1, 16);
        if (strip == 0) vL = 0.f;
        float vR = __shfl_down(A.x, 1, 16);
        if (strip == 15) vR = 0.f;

        const float vv[14] = { vL, A.x, A.y, A.z, A.w,
                               Bv.x, Bv.y, Bv.z, Bv.w,
                               Cv.x, Cv.y, Cv.z, Cv.w, vR };

        // input row r: TOP tap of out row i, MID of i-1, BOTTOM of i-2
        if (i < RB) {
            #pragma unroll
            for (int q = 0; q < 12; ++q)
                acc[i][q] = fmaf(w00, vv[q], fmaf(w01, vv[q+1], fmaf(w02, vv[q+2], acc[i][q])));
        }
        if (i >= 1 && i <= RB) {
            #pragma unroll
            for (int q = 0; q < 12; ++q)
                acc[i-1][q] = fmaf(w10, vv[q], fmaf(w11, vv[q+1], fmaf(w12, vv[q+2], acc[i-1][q])));
        }
        if (i >= 2) {
            #pragma unroll
            for (int q = 0; q < 12; ++q)
                acc[i-2][q] = fmaf(w20, vv[q], fmaf(w21, vv[q+1], fmaf(w22, vv[q+2], acc[i-2][q])));
        }
    }

    #pragma unroll
    for (int j = 0; j < RB; ++j) {
        float* po = out + (size_t)plane * PLANE + (y0 + j) * W + x0;
        floatx4 o0 = { acc[j][0], acc[j][1], acc[j][2],  acc[j][3]  };
        floatx4 o1 = { acc[j][4], acc[j][5], acc[j][6],  acc[j][7]  };
        floatx4 o2 = { acc[j][8], acc[j][9], acc[j][10], acc[j][11] };
        __builtin_nontemporal_store(o0, (floatx4*)po);
        __builtin_nontemporal_store(o1, (floatx4*)(po + 4));
        __builtin_nontemporal_store(o2, (floatx4*)(po + 8));
    }
}

extern "C" void kernel_launch(void* const* d_in, const int* in_sizes, int n_in,
                              void* d_out, int out_size, void* d_ws, size_t ws_size,
                              hipStream_t stream) {
    const float* x    = (const float*)d_in[0];
    const float* w1   = (const float*)d_in[1];
    const float* b1   = (const float*)d_in[2];
    const float* w2   = (const float*)d_in[3];
    const float* b2   = (const float*)d_in[4];
    const float* wb   = (const float*)d_in[5];
    const float* bias = (const float*)d_in[6];
    float* out = (float*)d_out;

    // workspace layout: pooled [2048] floats, cw [2048*9] floats
    float* pooled = (float*)d_ws;
    float* cw     = pooled + NPLANES;

    pool_kernel<<<NPLANES, 256, 0, stream>>>(x, pooled);
    selector_kernel<<<1, 512, 0, stream>>>(pooled, w1, b1, w2, b2, wb, cw);
    conv_kernel<<<NPLANES, 512, 0, stream>>>(x, cw, bias, out);
}

// Round 5
// 203.210 us; speedup vs baseline: 1.5382x; 1.5382x over previous
//
#include <hip/hip_runtime.h>
#include <hip/hip_bf16.h>

// Problem constants (from reference)
#define B 16
#define C 128
#define H 192
#define W 192
#define HID 32
#define K 2
#define PLANE (H*W)           // 36864
#define NPLANES (B*C)         // 2048
#define RB 8                  // output rows per thread (vertical register blocking)

typedef float floatx4 __attribute__((ext_vector_type(4)));

// ---------------- Kernel 1: global average pool per (b,c) plane ----------------
__global__ __launch_bounds__(256) void pool_kernel(const float* __restrict__ x,
                                                   float* __restrict__ pooled) {
    const int plane = blockIdx.x;  // b*C + c
    const float4* px4 = (const float4*)(x + (size_t)plane * PLANE);  // 9216 float4
    float s = 0.f;
    for (int i = threadIdx.x; i < PLANE / 4; i += 256) {
        float4 v = px4[i];
        s += v.x + v.y + v.z + v.w;
    }
    // wave64 reduce
    for (int off = 32; off; off >>= 1) s += __shfl_down(s, off, 64);
    __shared__ float wsum[4];
    const int lane = threadIdx.x & 63, wid = threadIdx.x >> 6;
    if (lane == 0) wsum[wid] = s;
    __syncthreads();
    if (threadIdx.x == 0) {
        pooled[plane] = (wsum[0] + wsum[1] + wsum[2] + wsum[3]) * (1.0f / (float)PLANE);
    }
}

// ---------------- Kernel 2: selector MLP + softmax + weight combine ----------------
__global__ __launch_bounds__(512) void selector_kernel(const float* __restrict__ pooled,
                                                       const float* __restrict__ w1,
                                                       const float* __restrict__ b1,
                                                       const float* __restrict__ w2,
                                                       const float* __restrict__ b2,
                                                       const float* __restrict__ wb,
                                                       float* __restrict__ cw) {
    __shared__ float h[B][HID];
    __shared__ float attn[B][K];
    const int tid = threadIdx.x;

    // h[b][j] = relu(sum_c pooled[b,c] * w1[j,c] + b1[j])   (512 = 16*32 threads)
    {
        const int b = tid >> 5, j = tid & 31;
        float s = b1[j];
        const float* pb = pooled + b * C;
        const float* wj = w1 + j * C;
        #pragma unroll 8
        for (int c = 0; c < C; ++c) s += pb[c] * wj[c];
        h[b][j] = fmaxf(s, 0.f);
    }
    __syncthreads();
    // logits[b][k]
    if (tid < B * K) {
        const int b = tid >> 1, k = tid & 1;
        float s = b2[k];
        const float* wk = w2 + k * HID;
        #pragma unroll
        for (int j = 0; j < HID; ++j) s += h[b][j] * wk[j];
        attn[b][k] = s;
    }
    __syncthreads();
    // softmax over K=2
    if (tid < B) {
        const float a0 = attn[tid][0], a1 = attn[tid][1];
        const float m = fmaxf(a0, a1);
        const float e0 = __expf(a0 - m), e1 = __expf(a1 - m);
        const float inv = 1.f / (e0 + e1);
        attn[tid][0] = e0 * inv;
        attn[tid][1] = e1 * inv;
    }
    __syncthreads();
    // cw[b][c][9] = attn[b][0]*wb[0][c][9] + attn[b][1]*wb[1][c][9]
    for (int i = tid; i < B * C * 9; i += 512) {
        const int b = i / (C * 9);
        const int ci = i % (C * 9);
        cw[i] = attn[b][0] * wb[ci] + attn[b][1] * wb[C * 9 + ci];
    }
}

// ---------------- Kernel 3: depthwise 3x3 conv (pad 1) + bias ----------------
// R3 structure (proven fast): thread = 4-wide x 8-tall tile, per-lane
// addresses CONTIGUOUS within each dwordx4 load/store (16 B/lane stride).
// Each input row loaded once (1 float4 + 2 scalar halo loads that hit L1)
// and feeds 3 output rows held in registers.
// Block = 576 threads (9 waves) = half a plane (12 bands x 48 col-strips).
// Planes iterate in REVERSE so conv reads the tail of x that pool_kernel
// left resident in the 256 MiB Infinity Cache (proven: FETCH 302->162 MB).
__global__ __launch_bounds__(576) void conv_kernel(const float* __restrict__ x,
                                                   const float* __restrict__ cw,
                                                   const float* __restrict__ bias,
                                                   float* __restrict__ out) {
    const int plane = (NPLANES - 1) - (blockIdx.x >> 1);  // reverse, block-uniform
    const int half  = blockIdx.x & 1;
    const int tid   = threadIdx.x;
    const int xq    = tid % 48;              // col strip (4 floats)
    const int band  = tid / 48 + half * 12;  // 0..23 (8-row band)
    const int c     = plane & (C - 1);

    const float* w = cw + plane * 9;
    const float w00 = w[0], w01 = w[1], w02 = w[2];
    const float w10 = w[3], w11 = w[4], w12 = w[5];
    const float w20 = w[6], w21 = w[7], w22 = w[8];
    const float bv = bias[c];

    const int x0 = xq * 4;
    const int y0 = band * RB;
    const float* px = x + (size_t)plane * PLANE;

    float acc[RB][4];
    #pragma unroll
    for (int j = 0; j < RB; ++j) {
        acc[j][0] = bv; acc[j][1] = bv; acc[j][2] = bv; acc[j][3] = bv;
    }

    #pragma unroll
    for (int i = 0; i < RB + 2; ++i) {
        const int r = y0 - 1 + i;
        float v0, v1, v2, v3, v4, v5;
        if (r >= 0 && r < H) {
            const float* rp = px + r * W + x0;
            const float4 cur = *(const float4*)rp;
            v1 = cur.x; v2 = cur.y; v3 = cur.z; v4 = cur.w;
            v0 = (x0 > 0)     ? rp[-1] : 0.f;
            v5 = (x0 + 4 < W) ? rp[4]  : 0.f;
        } else {
            v0 = v1 = v2 = v3 = v4 = v5 = 0.f;
        }
        // input row r is the TOP tap of out row i, MID of i-1, BOTTOM of i-2
        if (i < RB) {
            acc[i][0] = fmaf(w00, v0, fmaf(w01, v1, fmaf(w02, v2, acc[i][0])));
            acc[i][1] = fmaf(w00, v1, fmaf(w01, v2, fmaf(w02, v3, acc[i][1])));
            acc[i][2] = fmaf(w00, v2, fmaf(w01, v3, fmaf(w02, v4, acc[i][2])));
            acc[i][3] = fmaf(w00, v3, fmaf(w01, v4, fmaf(w02, v5, acc[i][3])));
        }
        if (i >= 1 && i <= RB) {
            acc[i-1][0] = fmaf(w10, v0, fmaf(w11, v1, fmaf(w12, v2, acc[i-1][0])));
            acc[i-1][1] = fmaf(w10, v1, fmaf(w11, v2, fmaf(w12, v3, acc[i-1][1])));
            acc[i-1][2] = fmaf(w10, v2, fmaf(w11, v3, fmaf(w12, v4, acc[i-1][2])));
            acc[i-1][3] = fmaf(w10, v3, fmaf(w11, v4, fmaf(w12, v5, acc[i-1][3])));
        }
        if (i >= 2) {
            acc[i-2][0] = fmaf(w20, v0, fmaf(w21, v1, fmaf(w22, v2, acc[i-2][0])));
            acc[i-2][1] = fmaf(w20, v1, fmaf(w21, v2, fmaf(w22, v3, acc[i-2][1])));
            acc[i-2][2] = fmaf(w20, v2, fmaf(w21, v3, fmaf(w22, v4, acc[i-2][2])));
            acc[i-2][3] = fmaf(w20, v3, fmaf(w21, v4, fmaf(w22, v5, acc[i-2][3])));
        }
    }

    float* po = out + (size_t)plane * PLANE + y0 * W + x0;
    #pragma unroll
    for (int j = 0; j < RB; ++j) {
        floatx4 o = { acc[j][0], acc[j][1], acc[j][2], acc[j][3] };
        __builtin_nontemporal_store(o, (floatx4*)(po + j * W));
    }
}

extern "C" void kernel_launch(void* const* d_in, const int* in_sizes, int n_in,
                              void* d_out, int out_size, void* d_ws, size_t ws_size,
                              hipStream_t stream) {
    const float* x    = (const float*)d_in[0];
    const float* w1   = (const float*)d_in[1];
    const float* b1   = (const float*)d_in[2];
    const float* w2   = (const float*)d_in[3];
    const float* b2   = (const float*)d_in[4];
    const float* wb   = (const float*)d_in[5];
    const float* bias = (const float*)d_in[6];
    float* out = (float*)d_out;

    // workspace layout: pooled [2048] floats, cw [2048*9] floats
    float* pooled = (float*)d_ws;
    float* cw     = pooled + NPLANES;

    pool_kernel<<<NPLANES, 256, 0, stream>>>(x, pooled);
    selector_kernel<<<1, 512, 0, stream>>>(pooled, w1, b1, w2, b2, wb, cw);
    conv_kernel<<<NPLANES * 2, 576, 0, stream>>>(x, cw, bias, out);
}